// Round 4
// baseline (1963.789 us; speedup 1.0000x reference)
//
#include <hip/hip_runtime.h>

// RankingLossL1: negative mining (L1 top-K) + margin ranking loss.
// N=50000 rows, D=128, T=1024 anchors/direction, K=10, GAMMA=1.
//
// Pipeline:
//   1) mine_kernel : per (dir, anchor-tile of 64, N-chunk) wave, each lane owns
//      one anchor (128 VGPRs), streams G rows (uniform-address broadcast
//      loads) through a QUARTER-ROW register double buffer (32+32 VGPRs —
//      full-row dbuf would blow the 256-VGPR budget and spill), accumulates
//      |a-g| with packed-fp32 diffs (v_pk_add_f32 neg_lo/neg_hi: 3 VALU inst
//      per 2 elements vs 4 scalar), keeps sorted top-10 in registers.
//      Block-index mapping is XCD-aware: blocks with equal bid%8 share only
//      8 chunks -> per-XCD G working set 3.2MB < 4MB L2.
//   2) merge_kernel: per (dir,anchor) thread merges 64 chunk top-10s
//      (transposed candidate layout -> coalesced both sides) -> negatives
//   3) zero + loss_kernel: one wave per t, shuffle-reduced L1 distances,
//      atomicAdd of relu-margin terms / (T*K).
//
// Top-k ties: only distance VALUES enter the loss sum, so boundary-tie index
// choices cannot change the scalar result beyond fp rounding.

#define NROWS 50000
#define DDIM  128
#define TT    1024
#define KK    10
#define NCH   64          // N-chunks (2*16*64 = 2048 waves = 8/CU * 256 CU)
#define CH    782         // ceil(NROWS/NCH)
#define TILES 16          // TT/64 anchor tiles
#define TT2   (2 * TT)    // candidate row stride (dir-major anchor slot)

// native vector types: safe as inline-asm "v" operands (HIP float2/float4 are
// class types and may be rejected by clang's asm operand checking)
typedef float f32x2 __attribute__((ext_vector_type(2)));
typedef float f32x4 __attribute__((ext_vector_type(4)));

// packed fp32 subtract: d = a - b on both halves, one VOP3P instruction
__device__ __forceinline__ f32x2 pk_sub(f32x2 a, f32x2 b) {
  f32x2 d;
  asm("v_pk_add_f32 %0, %1, %2 neg_lo:[0,1] neg_hi:[0,1]"
      : "=v"(d)
      : "v"(a), "v"(b));
  return d;
}

__device__ __forceinline__ void topk_insert(float (&val)[KK], int (&idx)[KK],
                                            float cv, int ci) {
  // fully unrolled sorted insert (ascending); static indices -> stays in VGPRs
#pragma unroll
  for (int i = 0; i < KK; i++) {
    const bool lt = cv < val[i];
    const float tv = lt ? val[i] : cv;
    const int ti = lt ? idx[i] : ci;
    val[i] = lt ? cv : val[i];
    idx[i] = lt ? ci : idx[i];
    cv = tv;
    ci = ti;
  }
}

__global__ __launch_bounds__(64, 2) void mine_kernel(
    const float* __restrict__ out1, const float* __restrict__ out2,
    const int* __restrict__ anc1, const int* __restrict__ anc2,
    float* __restrict__ cand_val, int* __restrict__ cand_idx) {
  const int lane = threadIdx.x;  // 0..63, one anchor per lane
  const int bid = blockIdx.x;
  // XCD-aware decode: bid = ((chunk>>3)*32 + combo)*8 + (chunk&7)
  // -> all blocks with equal bid%8 (same XCD under round-robin) share only
  //    8 distinct chunks: per-XCD row working set 8*400KB = 3.2MB < 4MB L2.
  const int chunk = ((bid >> 8) << 3) | (bid & 7);
  const int combo = (bid >> 3) & 31;  // dir*16 + tile
  const int dir = combo >> 4;
  const int tile = combo & 15;

  const float* __restrict__ A = dir ? out2 : out1;
  const float* __restrict__ G = dir ? out1 : out2;
  const int* __restrict__ anc = dir ? anc2 : anc1;

  const int a = tile * 64 + lane;  // anchor slot [0,1024)
  const int arow = anc[a];

  // anchor vector -> 64 f32x2 = 128 VGPRs (statically indexed)
  f32x2 av[DDIM / 2];
  {
    const f32x4* ap = (const f32x4*)(A + (size_t)arow * DDIM);
#pragma unroll
    for (int j = 0; j < DDIM / 4; j++) {
      const f32x4 v = ap[j];
      av[2 * j] = (f32x2){v.x, v.y};
      av[2 * j + 1] = (f32x2){v.z, v.w};
    }
  }

  float val[KK];
  int idx[KK];
#pragma unroll
  for (int i = 0; i < KK; i++) {
    val[i] = 3.4e38f;
    idx[i] = 0;
  }

  const int r0 = chunk * CH;
  const int r1 = (r0 + CH < NROWS) ? (r0 + CH) : NROWS;

  // quarter-row (32 floats = 8 f32x4) load into a ping-pong buffer
  auto LOADQ = [&](f32x4(&buf)[8], int row, int q) {
    const f32x4* gp = (const f32x4*)(G + (size_t)row * DDIM) + q * 8;
#pragma unroll
    for (int j = 0; j < 8; j++) buf[j] = gp[j];
  };
  // quarter-row packed-L1 accumulation: 16 pk_sub + 32 abs-adds
  auto COMPQ = [&](const f32x4(&buf)[8], int q, float& c0, float& c1,
                   float& c2, float& c3) {
#pragma unroll
    for (int j = 0; j < 8; j++) {
      const int e = q * 16 + 2 * j;  // f32x2 index into av
      const f32x2 glo = {buf[j].x, buf[j].y};
      const f32x2 ghi = {buf[j].z, buf[j].w};
      const f32x2 d0 = pk_sub(av[e], glo);
      const f32x2 d1 = pk_sub(av[e + 1], ghi);
      c0 += fabsf(d0.x);  // v_add_f32 with |.| input modifier
      c1 += fabsf(d0.y);
      c2 += fabsf(d1.x);
      c3 += fabsf(d1.y);
    }
  };

  f32x4 bufA[8], bufB[8];
  LOADQ(bufA, r0, 0);
  for (int r = r0; r < r1; r++) {
    float c0 = 0.f, c1 = 0.f, c2 = 0.f, c3 = 0.f;
    LOADQ(bufB, r, 1);
    COMPQ(bufA, 0, c0, c1, c2, c3);
    LOADQ(bufA, r, 2);
    COMPQ(bufB, 1, c0, c1, c2, c3);
    LOADQ(bufB, r, 3);
    COMPQ(bufA, 2, c0, c1, c2, c3);
    {
      const int nr = (r + 1 < r1) ? r + 1 : r0;  // wrap: always a valid row
      LOADQ(bufA, nr, 0);
    }
    COMPQ(bufB, 3, c0, c1, c2, c3);
    const float acc = (c0 + c1) + (c2 + c3);
    if (acc < val[KK - 1]) topk_insert(val, idx, acc, r);
  }

  // candidate layout [chunk][k][dir*TT + a]: 64 contiguous floats per
  // (chunk,k) -> coalesced mine-write AND coalesced merge-read.
  const int slot = dir * TT + a;
#pragma unroll
  for (int i = 0; i < KK; i++) {
    const size_t o = (size_t)(chunk * KK + i) * TT2 + slot;
    cand_val[o] = val[i];
    cand_idx[o] = idx[i];
  }
}

__global__ void merge_kernel(const float* __restrict__ cand_val,
                             const int* __restrict__ cand_idx,
                             int* __restrict__ neg) {
  const int tid = blockIdx.x * blockDim.x + threadIdx.x;  // dir*TT + anchor
  if (tid >= TT2) return;
  float val[KK];
  int idx[KK];
#pragma unroll
  for (int i = 0; i < KK; i++) {
    val[i] = 3.4e38f;
    idx[i] = 0;
  }
  // chunks ascending, k ascending: stable lowest-row-index tie order
  for (int c = 0; c < NCH * KK; c++) {
    const float v = cand_val[(size_t)c * TT2 + tid];
    if (v < val[KK - 1]) topk_insert(val, idx, v, cand_idx[(size_t)c * TT2 + tid]);
  }
#pragma unroll
  for (int i = 0; i < KK; i++) neg[(size_t)tid * KK + i] = idx[i];
}

__global__ void zero_kernel(float* __restrict__ out) {
  if (threadIdx.x == 0) out[0] = 0.f;
}

__global__ void loss_kernel(const float* __restrict__ out1,
                            const float* __restrict__ out2,
                            const int* __restrict__ anc1,
                            const int* __restrict__ anc2,
                            const int* __restrict__ neg,  // [2][TT][KK]
                            float* __restrict__ out) {
  const int lane = threadIdx.x & 63;
  const int w = threadIdx.x >> 6;
  const int t = blockIdx.x * 4 + w;  // one wave per t
  const int a1 = anc1[t];
  const int a2 = anc2[t];
  const int e = lane * 2;  // 2 elements per lane

  const f32x2 x1 = *(const f32x2*)(out1 + (size_t)a1 * DDIM + e);
  const f32x2 x2 = *(const f32x2*)(out2 + (size_t)a2 * DDIM + e);

  float ap = fabsf(x1.x - x2.x) + fabsf(x1.y - x2.y);
#pragma unroll
  for (int o = 32; o > 0; o >>= 1) ap += __shfl_xor(ap, o, 64);
  const float Dm = ap + 1.0f;  // GAMMA = 1

  float s = 0.f;
  for (int k = 0; k < KK; k++) {
    const int n1 = neg[(size_t)t * KK + k];         // row of out2
    const int n2 = neg[(size_t)(TT + t) * KK + k];  // row of out1
    const f32x2 v1 = *(const f32x2*)(out2 + (size_t)n1 * DDIM + e);
    const f32x2 v2 = *(const f32x2*)(out1 + (size_t)n2 * DDIM + e);
    float d1 = fabsf(x1.x - v1.x) + fabsf(x1.y - v1.y);
    float d2 = fabsf(x2.x - v2.x) + fabsf(x2.y - v2.y);
#pragma unroll
    for (int o = 32; o > 0; o >>= 1) {
      d1 += __shfl_xor(d1, o, 64);
      d2 += __shfl_xor(d2, o, 64);
    }
    s += fmaxf(Dm - d1, 0.f) + fmaxf(Dm - d2, 0.f);
  }
  if (lane == 0) atomicAdd(out, s * (1.0f / (TT * KK)));
}

extern "C" void kernel_launch(void* const* d_in, const int* in_sizes, int n_in,
                              void* d_out, int out_size, void* d_ws,
                              size_t ws_size, hipStream_t stream) {
  const float* out1 = (const float*)d_in[0];
  const float* out2 = (const float*)d_in[1];
  const int* anc1 = (const int*)d_in[2];
  const int* anc2 = (const int*)d_in[3];

  // workspace: cand_val (5.24MB) | cand_idx (5.24MB) | neg (80KB)  ~= 10.6MB
  float* cand_val = (float*)d_ws;
  int* cand_idx = (int*)(cand_val + (size_t)NCH * KK * TT2);
  int* neg = cand_idx + (size_t)NCH * KK * TT2;
  float* out = (float*)d_out;

  hipLaunchKernelGGL(mine_kernel, dim3(2 * TILES * NCH), dim3(64), 0, stream,
                     out1, out2, anc1, anc2, cand_val, cand_idx);
  hipLaunchKernelGGL(merge_kernel, dim3(8), dim3(256), 0, stream, cand_val,
                     cand_idx, neg);
  hipLaunchKernelGGL(zero_kernel, dim3(1), dim3(64), 0, stream, out);
  hipLaunchKernelGGL(loss_kernel, dim3(TT / 4), dim3(256), 0, stream, out1,
                     out2, anc1, anc2, neg, out);
}

// Round 5
// 1385.614 us; speedup vs baseline: 1.4173x; 1.4173x over previous
//
#include <hip/hip_runtime.h>
#include <stdint.h>

// RankingLossL1: negative mining (L1 top-K) + margin ranking loss.
// N=50000 rows, D=128, T=1024 anchors/direction, K=10, GAMMA=1.
//
// Round-5 structure (post-mortem of r4: VGPR_Count=100 showed the allocator
// dropped the anchor vector out of registers; inline-asm pk_sub blamed):
//   * NO inline asm in the hot loop — plain f32x2 math, compiler packs.
//   * G rows stream through double-buffered 16-row LDS tiles staged with
//     __builtin_amdgcn_global_load_lds (no VGPR cost, latency hidden by a
//     full tile of compute). One wave per block -> no barriers, just vmcnt.
//   * Anchor vector (128 VGPRs) + top-k stay register-resident (~190 VGPR).
//
// Top-k ties: only distance VALUES enter the loss sum, so boundary-tie index
// choices cannot change the scalar result beyond fp rounding.

#define NROWS 50000
#define DDIM  128
#define TT    1024
#define KK    10
#define NCH   64          // N-chunks (2*16*64 = 2048 waves = 8/CU * 256 CU)
#define CH    782         // ceil(NROWS/NCH)
#define TILES 16          // TT/64 anchor tiles
#define TT2   (2 * TT)    // candidate row stride (dir-major anchor slot)
#define TROWS 16          // G rows per LDS tile (16*512B = 8KB; x2 buffers)

typedef float f32x2 __attribute__((ext_vector_type(2)));
typedef float f32x4 __attribute__((ext_vector_type(4)));

__device__ __forceinline__ void topk_insert(float (&val)[KK], int (&idx)[KK],
                                            float cv, int ci) {
  // fully unrolled sorted insert (ascending); static indices -> stays in VGPRs
#pragma unroll
  for (int i = 0; i < KK; i++) {
    const bool lt = cv < val[i];
    const float tv = lt ? val[i] : cv;
    const int ti = lt ? idx[i] : ci;
    val[i] = lt ? cv : val[i];
    idx[i] = lt ? ci : idx[i];
    cv = tv;
    ci = ti;
  }
}

__global__ __launch_bounds__(64, 2) void mine_kernel(
    const float* __restrict__ out1, const float* __restrict__ out2,
    const int* __restrict__ anc1, const int* __restrict__ anc2,
    float* __restrict__ cand_val, int* __restrict__ cand_idx) {
  const int lane = threadIdx.x;  // 0..63, one anchor per lane
  const int bid = blockIdx.x;
  // XCD-aware decode: blocks with equal bid%8 (same XCD under round-robin)
  // share only 8 distinct chunks -> per-XCD G working set 3.2MB < 4MB L2.
  const int chunk = ((bid >> 8) << 3) | (bid & 7);
  const int combo = (bid >> 3) & 31;  // dir*16 + tile
  const int dir = combo >> 4;
  const int tile = combo & 15;

  const float* __restrict__ A = dir ? out2 : out1;
  const float* __restrict__ G = dir ? out1 : out2;
  const int* __restrict__ anc = dir ? anc2 : anc1;

  const int a = tile * 64 + lane;  // anchor slot [0,1024)
  const int arow = anc[a];

  // anchor vector -> 64 f32x2 = 128 VGPRs (statically indexed)
  f32x2 av[DDIM / 2];
  {
    const f32x4* ap = (const f32x4*)(A + (size_t)arow * DDIM);
#pragma unroll
    for (int j = 0; j < DDIM / 4; j++) {
      const f32x4 v = ap[j];
      av[2 * j] = (f32x2){v.x, v.y};
      av[2 * j + 1] = (f32x2){v.z, v.w};
    }
  }

  float val[KK];
  int idx[KK];
#pragma unroll
  for (int i = 0; i < KK; i++) {
    val[i] = 3.4e38f;
    idx[i] = 0;
  }

  const int r0 = chunk * CH;
  const int r1 = (r0 + CH < NROWS) ? (r0 + CH) : NROWS;
  const int nt = (r1 - r0 + TROWS - 1) / TROWS;  // tiles in this chunk

  // double-buffered G tiles in LDS; single wave per block -> no barriers
  __shared__ float gt[2][TROWS * DDIM];

  // stage TROWS rows starting at rs into buffer b: 8 calls x (64 lanes x 16B)
  auto STAGE = [&](int b, int rs) {
    const float* gsrc = G + (size_t)rs * DDIM + lane * 4;
    float* ldst = &gt[b][0];
#pragma unroll
    for (int c = 0; c < (TROWS * DDIM) / 256; c++) {
      __builtin_amdgcn_global_load_lds(
          (const __attribute__((address_space(1))) uint32_t*)(gsrc + c * 256),
          (__attribute__((address_space(3))) uint32_t*)(ldst + c * 256),
          16, 0, 0);
    }
  };

  // clamp a tile's source start so staging never reads past row NROWS
  auto RS = [&](int ts) { return ts > NROWS - TROWS ? NROWS - TROWS : ts; };

  STAGE(0, RS(r0));
  asm volatile("s_waitcnt vmcnt(0)" ::: "memory");

  int buf = 0;
  for (int t = 0; t < nt; t++) {
    const int ts = r0 + t * TROWS;
    const int rs = RS(ts);
    if (t + 1 < nt) STAGE(buf ^ 1, RS(ts + TROWS));  // overlap with compute

    const int rend = (ts + TROWS < r1) ? ts + TROWS : r1;
    for (int r = ts; r < rend; r++) {
      const f32x4* lp = (const f32x4*)&gt[buf][(r - rs) * DDIM];
      float c0 = 0.f, c1 = 0.f, c2 = 0.f, c3 = 0.f;  // 4 independent chains
#pragma unroll
      for (int j = 0; j < DDIM / 4; j++) {
        const f32x4 g = lp[j];  // uniform addr -> broadcast, conflict-free
        const f32x2 d0 = av[2 * j] - (f32x2){g.x, g.y};
        const f32x2 d1 = av[2 * j + 1] - (f32x2){g.z, g.w};
        c0 += fabsf(d0.x);  // v_add_f32 with |.| input modifier
        c1 += fabsf(d0.y);
        c2 += fabsf(d1.x);
        c3 += fabsf(d1.y);
      }
      const float acc = (c0 + c1) + (c2 + c3);
      if (acc < val[KK - 1]) topk_insert(val, idx, acc, r);
    }
    asm volatile("s_waitcnt vmcnt(0)" ::: "memory");  // next tile landed
    buf ^= 1;
  }

  // candidate layout [chunk][k][dir*TT + a]: 64 contiguous floats per
  // (chunk,k) -> coalesced mine-write AND coalesced merge-read.
  const int slot = dir * TT + a;
#pragma unroll
  for (int i = 0; i < KK; i++) {
    const size_t o = (size_t)(chunk * KK + i) * TT2 + slot;
    cand_val[o] = val[i];
    cand_idx[o] = idx[i];
  }
}

__global__ void merge_kernel(const float* __restrict__ cand_val,
                             const int* __restrict__ cand_idx,
                             int* __restrict__ neg) {
  const int tid = blockIdx.x * blockDim.x + threadIdx.x;  // dir*TT + anchor
  if (tid >= TT2) return;
  float val[KK];
  int idx[KK];
#pragma unroll
  for (int i = 0; i < KK; i++) {
    val[i] = 3.4e38f;
    idx[i] = 0;
  }
  // chunks ascending, k ascending: stable lowest-row-index tie order
  for (int c = 0; c < NCH * KK; c++) {
    const float v = cand_val[(size_t)c * TT2 + tid];
    if (v < val[KK - 1]) topk_insert(val, idx, v, cand_idx[(size_t)c * TT2 + tid]);
  }
#pragma unroll
  for (int i = 0; i < KK; i++) neg[(size_t)tid * KK + i] = idx[i];
}

__global__ void zero_kernel(float* __restrict__ out) {
  if (threadIdx.x == 0) out[0] = 0.f;
}

__global__ void loss_kernel(const float* __restrict__ out1,
                            const float* __restrict__ out2,
                            const int* __restrict__ anc1,
                            const int* __restrict__ anc2,
                            const int* __restrict__ neg,  // [2][TT][KK]
                            float* __restrict__ out) {
  const int lane = threadIdx.x & 63;
  const int w = threadIdx.x >> 6;
  const int t = blockIdx.x * 4 + w;  // one wave per t
  const int a1 = anc1[t];
  const int a2 = anc2[t];
  const int e = lane * 2;  // 2 elements per lane

  const f32x2 x1 = *(const f32x2*)(out1 + (size_t)a1 * DDIM + e);
  const f32x2 x2 = *(const f32x2*)(out2 + (size_t)a2 * DDIM + e);

  float ap = fabsf(x1.x - x2.x) + fabsf(x1.y - x2.y);
#pragma unroll
  for (int o = 32; o > 0; o >>= 1) ap += __shfl_xor(ap, o, 64);
  const float Dm = ap + 1.0f;  // GAMMA = 1

  float s = 0.f;
  for (int k = 0; k < KK; k++) {
    const int n1 = neg[(size_t)t * KK + k];         // row of out2
    const int n2 = neg[(size_t)(TT + t) * KK + k];  // row of out1
    const f32x2 v1 = *(const f32x2*)(out2 + (size_t)n1 * DDIM + e);
    const f32x2 v2 = *(const f32x2*)(out1 + (size_t)n2 * DDIM + e);
    float d1 = fabsf(x1.x - v1.x) + fabsf(x1.y - v1.y);
    float d2 = fabsf(x2.x - v2.x) + fabsf(x2.y - v2.y);
#pragma unroll
    for (int o = 32; o > 0; o >>= 1) {
      d1 += __shfl_xor(d1, o, 64);
      d2 += __shfl_xor(d2, o, 64);
    }
    s += fmaxf(Dm - d1, 0.f) + fmaxf(Dm - d2, 0.f);
  }
  if (lane == 0) atomicAdd(out, s * (1.0f / (TT * KK)));
}

extern "C" void kernel_launch(void* const* d_in, const int* in_sizes, int n_in,
                              void* d_out, int out_size, void* d_ws,
                              size_t ws_size, hipStream_t stream) {
  const float* out1 = (const float*)d_in[0];
  const float* out2 = (const float*)d_in[1];
  const int* anc1 = (const int*)d_in[2];
  const int* anc2 = (const int*)d_in[3];

  // workspace: cand_val (5.24MB) | cand_idx (5.24MB) | neg (80KB)  ~= 10.6MB
  float* cand_val = (float*)d_ws;
  int* cand_idx = (int*)(cand_val + (size_t)NCH * KK * TT2);
  int* neg = cand_idx + (size_t)NCH * KK * TT2;
  float* out = (float*)d_out;

  hipLaunchKernelGGL(mine_kernel, dim3(2 * TILES * NCH), dim3(64), 0, stream,
                     out1, out2, anc1, anc2, cand_val, cand_idx);
  hipLaunchKernelGGL(merge_kernel, dim3(8), dim3(256), 0, stream, cand_val,
                     cand_idx, neg);
  hipLaunchKernelGGL(zero_kernel, dim3(1), dim3(64), 0, stream, out);
  hipLaunchKernelGGL(loss_kernel, dim3(TT / 4), dim3(256), 0, stream, out1,
                     out2, anc1, anc2, neg, out);
}